// Round 4
// baseline (136.987 us; speedup 1.0000x reference)
//
#include <hip/hip_runtime.h>
#include <math.h>

// Problem constants (fixed by the reference).
#define NITEMS 50000
#define BATCH  512
#define LLEN   50
#define KTOP   20
#define HDIM   32
#define DDIM   32
#define NCH    5
#define NSEG   33             // H+1 piecewise-linear segments
#define NSCAL  200            // scalars per item
#define NCELL  100            // (c,k) cells
#define THRP   33             // padded LDS stride for sorted thresholds
#define NWAVE  8              // waves per block
#define CSLOT  13             // ceil(100/8) cells per 8-lane group

typedef _Float16 h2 __attribute__((ext_vector_type(2)));

static __device__ __forceinline__ float dot2_acc(h2 a, h2 b, float c) {
#if __has_builtin(__builtin_amdgcn_fdot2)
    return __builtin_amdgcn_fdot2(a, b, c, false);
#else
    return fmaf((float)a.x, (float)b.x, fmaf((float)a.y, (float)b.y, c));
#endif
}

// ---------------------------------------------------------------------------
// R15: same arithmetic as R14 (absmax 0.0 proven), prologue re-SCHEDULED:
//   * Build split into load->scan(pk[33] regs, full unroll)->write passes.
//     R14 interleaved LDS writes with overlay-cast LDS reads -> compiler
//     could not prove no-alias -> 33-deep serialized (LDS+L2) chain (~6us).
//     Now no LDS write precedes any read: everything pipelines (~0.3us).
//   * Rank pass stages w1/b1/W2-row-offset in RANK order (overlay on
//     sxo[6]/sxo[7], dead until waves 6/7's stripe phase post-build-barrier)
//     so the scan has no runtime-indexed register arrays (rule #20).
//   * Rank->row lookup is now WAVE-REDUNDANT (shfl prefix-scan of the
//     histogram): b is a register in every wave right after BAR2, so all
//     waves issue their ctx prefetches BEFORE the build barrier -- HBM
//     latency hides under the build instead of after it.  sBp removed.
// Main body from the target phase onward is R13/R11 VERBATIM
// (spill-fragile; do NOT restructure the stripe loop without checking
// WRITE_SIZE for spills).
// ---------------------------------------------------------------------------
__global__ __launch_bounds__(512, 4) void cnn_main(
        const float* __restrict__ ctx,
        const float* __restrict__ W1g, const float* __restrict__ b1g,
        const float* __restrict__ W2g, const float* __restrict__ b2g,
        const float* __restrict__ Wout, const float* __restrict__ bout,
        const int* __restrict__ item_idxs, const int* __restrict__ user_items,
        const int* __restrict__ user_lens,
        float* __restrict__ out) {
    __shared__ unsigned int sAB16[NCH*NSEG*32];  // 21120 B, swizzled fp16
    __shared__ float  sThrS[NCH*THRP];           // sorted thr, stride 33
    __shared__ uint2  sxo[NWAVE][NCELL];         // {x0h|off0<<16, x1h|off1<<16}
    __shared__ uint2  sWt[NCELL*8];              // [cell*8+d4] target wt bits
    __shared__ float  pRed[NWAVE][NCELL];        // per-wave scalar partials

    const int tid  = threadIdx.x;
    const int w    = tid >> 6;              // wave 0..7
    const int lane = tid & 63;
    const int g    = lane >> 3;             // cell sub-group 0..7
    const int d4   = lane & 7;              // covers d = 4*d4 .. 4*d4+3

    // Sorted pairing (ranks r and 511-r co-resident under round-robin).
    const int rank = (blockIdx.x < 256) ? blockIdx.x : (767 - blockIdx.x);

    // ---- prologue temporaries overlaid on later-phase LDS ----------------
    // pRed (3200 B): first written in the epilogue.
    // sWt head (204 B): sHist; first real write in the target phase.
    // sxo[6]/sxo[7] (800 B each): rank-order staging; waves 6/7 first write
    //   them in stripe phase S, which is after the build barrier.
    float* sW1f  = &pRed[0][0];                  // 160 f  (h-order)
    float* sB1f  = sW1f + NCH*HDIM;              // 160 f  (h-order)
    float* sThrT = sB1f + NCH*HDIM;              // 160 f
    int*   sInv  = (int*)(sThrT + NCH*HDIM);     // 160 i  (rank -> W2 row off)
    int*   sHist = (int*)&sWt[0];                // 51 i   (raw counts)
    float* sW1r  = (float*)&sxo[6][0];           // 160 f  (rank-order)
    float* sB1r  = (float*)&sxo[7][0];           // 160 f  (rank-order)

    // ---- B0..B1: stage W1/b1, zero histogram -----------------------------
    for (int i = tid; i < NCH*HDIM; i += 512) { sW1f[i] = W1g[i]; sB1f[i] = b1g[i]; }
    if (tid <= LLEN) sHist[tid] = 0;
    __syncthreads();

    // ---- B1..B2: thresholds; length histogram ----------------------------
    for (int i = tid; i < NCH*HDIM; i += 512) {
        float wv = sW1f[i];
        sThrT[i] = (wv != 0.f) ? (-sB1f[i] / wv) : INFINITY;
    }
    atomicAdd(&sHist[user_lens[tid]], 1);        // counts are order-invariant
    __syncthreads();

    // ---- B2..B3: wave-redundant rank->row scan; rank pass ----------------
    // Every wave independently resolves b (deterministic: same inputs, same
    // stable tie-break) -- no LDS round-trip, no serial tid0 prefix.
    int bsel = rank;                             // in-bounds fallback
    {
        int cnt = (lane >= 1 && lane <= LLEN) ? sHist[lane] : 0;
        int ex = cnt;
#pragma unroll
        for (int o = 1; o < 64; o <<= 1) {
            int t = __shfl_up(ex, o, 64);
            if (lane >= o) ex += t;
        }
        ex -= cnt;                               // exclusive prefix
        bool inb = (lane >= 1 && lane <= LLEN) && (ex <= rank) && (rank < ex + cnt);
        unsigned long long mm = __ballot(inb);
        if (mm != 0ull) {
            int lstar = (int)__builtin_ctzll(mm);
            int need = rank - __shfl(ex, lstar, 64);
            if (need < 0) need = 0;
            for (int chunk = 0; chunk < BATCH/64; ++chunk) {
                int j = (chunk << 6) + lane;
                unsigned long long mb = __ballot(user_lens[j] == lstar);
                int cntc = __popcll(mb);
                if (need < cntc) {               // wave-uniform condition
                    bool me = ((mb >> lane) & 1ull) &&
                              (__popcll(mb & ((1ull << lane) - 1ull)) == need);
                    unsigned long long ms = __ballot(me);
                    bsel = (chunk << 6) + (int)__builtin_ctzll(ms);
                    break;
                }
                need -= cntc;
            }
        }
    }
    // Rank pass: sorted thresholds + rank-order staging of w1/b1/W2-offset.
    for (int i = tid; i < NCH*HDIM; i += 512) {
        int c = i >> 5, h = i & 31;
        float thr = sThrT[i];
        int rnk = 0;
        for (int hh = 0; hh < HDIM; ++hh) {
            float t2 = sThrT[(c<<5) + hh];
            rnk += (t2 < thr || (t2 == thr && hh < h)) ? 1 : 0;
        }
        sThrS[c*THRP + rnk] = thr;
        sW1r[(c<<5) + rnk] = sW1f[i];
        sB1r[(c<<5) + rnk] = sB1f[i];
        sInv[(c<<5) + rnk] = i << 5;             // W2 row offset (i = c*32+h)
    }
    __syncthreads();

    // ---- main-body setup + prefetch issue (pre-build: hides under it) ----
    const int b    = bsel & (BATCH - 1);    // never out of bounds
    const int len  = user_lens[b];          // >= 1
    const float inv_len = 1.f / (float)len;
    const float bo = bout[0];
    const h2 wv0 = {(_Float16)Wout[4*d4],     (_Float16)Wout[4*d4 + 1]};
    const h2 wv1 = {(_Float16)Wout[4*d4 + 2], (_Float16)Wout[4*d4 + 3]};

    // Per-(lane,round) phase-S constants (fixed across items).
    int sc[4], sdst[4];
#pragma unroll
    for (int r = 0; r < 4; ++r) {
        int idx  = lane + 64*r;
        int c    = idx / 40, rr = idx - c*40;
        int cell = c*KTOP + (rr % KTOP);
        sc[r]   = c;
        sdst[r] = cell*8 + (rr / KTOP)*4;   // byte offset in sxo[w]
    }

    const int nstripe = (len > w) ? ((len - w + NWAVE - 1) / NWAVE) : 0;

    // Prefetch this wave's first stripe item + wave 0's target row now:
    // global loads only, consumed after the build barrier.
    float xp[4] = {0.f, 0.f, 0.f, 0.f};
    if (nstripe > 0) {
        const float* row = ctx + (size_t)user_items[b*LLEN + w] * NSCAL;
#pragma unroll
        for (int r = 0; r < 4; ++r) {
            int idx = lane + 64*r;
            if (idx < NSCAL) xp[r] = row[idx];
        }
    }
    float xt[4] = {0.f, 0.f, 0.f, 0.f};
    if (w == 0) {
        const float* row = ctx + (size_t)item_idxs[b] * NSCAL;
#pragma unroll
        for (int r = 0; r < 4; ++r) {
            int idx = lane + 64*r;
            if (idx < NSCAL) xt[r] = row[idx];
        }
    }

    // ---- B3..B4: AB build, three-pass (loads -> reg scan -> LDS writes) --
    if (tid < NCH*DDIM) {
        const int c = tid >> 5, d = tid & 31;
        const int cb = c << 5;
        // Pass 1: suffix totals, h-order (identical arithmetic to R14).
        float sa = 0.f, sb = 0.f, zb = 0.f;
#pragma unroll
        for (int h = 0; h < HDIM; ++h) {
            float wv = sW1f[cb + h];
            float bb = sB1f[cb + h];
            float w2 = W2g[((cb + h) << 5) + d];
            float aw = wv * w2, bw = bb * w2;
            if (wv < 0.f) { sa += aw; sb += bw; }
            else if (wv == 0.f && bb > 0.f) zb += bw;
        }
        const float b2v = b2g[cb + d] + zb;
        // Pass 2: rank-order scan into compile-time-indexed registers.
        // All LDS reads precede all LDS writes -> fully pipelinable.
        unsigned int pk[NSEG];
        float pa = 0.f, pb = 0.f;
#pragma unroll
        for (int s = 0; s < NSEG; ++s) {
            _Float16 ah = (_Float16)(pa + sa);
            _Float16 bh = (_Float16)(pb + sb + b2v);
            pk[s] = (unsigned int)__builtin_bit_cast(unsigned short, ah)
                  | ((unsigned int)__builtin_bit_cast(unsigned short, bh) << 16);
            if (s < HDIM) {
                float wv = sW1r[cb + s];             // rank-order staged
                float bb = sB1r[cb + s];
                float w2 = W2g[sInv[cb + s] + d];
                float aw = wv * w2, bw = bb * w2;
                if (wv > 0.f)      { pa += aw; pb += bw; }   // joins prefix
                else if (wv < 0.f) { sa -= aw; sb -= bw; }   // leaves suffix
            }
        }
        // Pass 3: swizzled fp16 writes (same layout as always).
        unsigned short* ab = (unsigned short*)sAB16;
        const int dq = d >> 2, dd = d & 3;
        const int sub = 4*(dd>>1) + (dd&1);
#pragma unroll
        for (int s = 0; s < NSEG; ++s) {
            int base = ((c*NSEG + s)*32 + dq*4)*2;          // ushort index
            ab[base + sub]     = (unsigned short)(pk[s] & 0xffffu);
            ab[base + sub + 2] = (unsigned short)(pk[s] >> 16);
        }
    }
    __syncthreads();                        // sAB16 + sThrS ready; xp/xt landed

    // ======================================================================
    // From here on: R13 main body, verbatim (xt preloaded above).
    // ======================================================================
    unsigned int wtA[CSLOT], wtB[CSLOT];    // target rep * Wout (h2 bits)
    float acc[CSLOT];
#pragma unroll
    for (int i = 0; i < CSLOT; ++i) acc[i] = 0.f;

    char* sxoB = (char*)&sxo[w][0];

    // ======== target item: wave 0 only, broadcast via sWt ================
    if (w == 0) {
#pragma unroll
        for (int r = 0; r < 4; ++r) {
            int idx = lane + 64*r;
            if (idx < NSCAL) {
                float xv = xt[r];
                int base = sc[r]*THRP;
                int pos = 0;
                pos += (sThrS[base + pos + 15] < xv) ? 16 : 0;
                pos += (sThrS[base + pos + 7]  < xv) ? 8  : 0;
                pos += (sThrS[base + pos + 3]  < xv) ? 4  : 0;
                pos += (sThrS[base + pos + 1]  < xv) ? 2  : 0;
                pos += (sThrS[base + pos]      < xv) ? 1  : 0;
                unsigned int off = (unsigned int)((sc[r]*NSEG + pos) << 7);
                _Float16 xh = (_Float16)xv;
                unsigned int word = (unsigned int)__builtin_bit_cast(unsigned short, xh)
                                  | (off << 16);
                *(unsigned int*)(sxoB + sdst[r]) = word;
            }
        }
        __builtin_amdgcn_wave_barrier();
#pragma unroll
        for (int i = 0; i < CSLOT; ++i) {
            int cell = g + 8*i;
            if (cell < NCELL) {
                uint2 xo = sxo[0][cell];
                const uint4* p0 = (const uint4*)((const char*)sAB16 + (xo.x >> 16) + (d4 << 4));
                const uint4* p1 = (const uint4*)((const char*)sAB16 + (xo.y >> 16) + (d4 << 4));
                uint4 q0 = *p0, q1 = *p1;
                _Float16 x0h = __builtin_bit_cast(_Float16, (unsigned short)(xo.x & 0xffffu));
                _Float16 x1h = __builtin_bit_cast(_Float16, (unsigned short)(xo.y & 0xffffu));
                h2 x0 = {x0h, x0h}, x1 = {x1h, x1h};
                h2 repa = (x0 * __builtin_bit_cast(h2, q0.x) + __builtin_bit_cast(h2, q0.y))
                        * (x1 * __builtin_bit_cast(h2, q1.x) + __builtin_bit_cast(h2, q1.y));
                h2 repb = (x0 * __builtin_bit_cast(h2, q0.z) + __builtin_bit_cast(h2, q0.w))
                        * (x1 * __builtin_bit_cast(h2, q1.z) + __builtin_bit_cast(h2, q1.w));
                wtA[i] = __builtin_bit_cast(unsigned int, (h2)(repa * wv0));
                wtB[i] = __builtin_bit_cast(unsigned int, (h2)(repb * wv1));
                sWt[cell*8 + d4] = make_uint2(wtA[i], wtB[i]);
            }
        }
    }
    __syncthreads();                        // sWt ready for all waves

    if (w != 0) {
#pragma unroll
        for (int i = 0; i < CSLOT; ++i) {
            int cell = g + 8*i;
            if (cell < NCELL) {
                uint2 v = sWt[cell*8 + d4];
                wtA[i] = v.x; wtB[i] = v.y;
            }
        }
    }

    // ======== stripe items (this wave only; no per-item barriers) ========
    for (int j = 0; j < nstripe; ++j) {
        float xc[4];
#pragma unroll
        for (int r = 0; r < 4; ++r) xc[r] = xp[r];

        // prefetch next stripe item (latency hidden behind S+C)
        if (j + 1 < nstripe) {
            const float* row = ctx + (size_t)user_items[b*LLEN + w + NWAVE*(j+1)] * NSCAL;
#pragma unroll
            for (int r = 0; r < 4; ++r) {
                int idx = lane + 64*r;
                if (idx < NSCAL) xp[r] = row[idx];
            }
        }

        // ---- phase S: binary-search segment, pack {fp16(x)|rowoff} ------
#pragma unroll
        for (int r = 0; r < 4; ++r) {
            int idx = lane + 64*r;
            if (idx < NSCAL) {
                float xv = xc[r];
                int base = sc[r]*THRP;
                int pos = 0;
                pos += (sThrS[base + pos + 15] < xv) ? 16 : 0;
                pos += (sThrS[base + pos + 7]  < xv) ? 8  : 0;
                pos += (sThrS[base + pos + 3]  < xv) ? 4  : 0;
                pos += (sThrS[base + pos + 1]  < xv) ? 2  : 0;
                pos += (sThrS[base + pos]      < xv) ? 1  : 0;
                unsigned int off = (unsigned int)((sc[r]*NSEG + pos) << 7);
                _Float16 xh = (_Float16)xv;
                unsigned int word = (unsigned int)__builtin_bit_cast(unsigned short, xh)
                                  | (off << 16);
                *(unsigned int*)(sxoB + sdst[r]) = word;
            }
        }
        __builtin_amdgcn_wave_barrier();

        // ---- phase C: 100 cells x 32 d by this wave alone ----------------
#pragma unroll
        for (int i = 0; i < CSLOT; ++i) {
            int cell = g + 8*i;
            if (cell < NCELL) {
                uint2 xo = sxo[w][cell];
                const uint4* p0 = (const uint4*)((const char*)sAB16 + (xo.x >> 16) + (d4 << 4));
                const uint4* p1 = (const uint4*)((const char*)sAB16 + (xo.y >> 16) + (d4 << 4));
                uint4 q0 = *p0, q1 = *p1;
                _Float16 x0h = __builtin_bit_cast(_Float16, (unsigned short)(xo.x & 0xffffu));
                _Float16 x1h = __builtin_bit_cast(_Float16, (unsigned short)(xo.y & 0xffffu));
                h2 x0 = {x0h, x0h}, x1 = {x1h, x1h};
                h2 repa = (x0 * __builtin_bit_cast(h2, q0.x) + __builtin_bit_cast(h2, q0.y))
                        * (x1 * __builtin_bit_cast(h2, q1.x) + __builtin_bit_cast(h2, q1.y));
                h2 repb = (x0 * __builtin_bit_cast(h2, q0.z) + __builtin_bit_cast(h2, q0.w))
                        * (x1 * __builtin_bit_cast(h2, q1.z) + __builtin_bit_cast(h2, q1.w));
                acc[i] = dot2_acc(repa, __builtin_bit_cast(h2, wtA[i]),
                         dot2_acc(repb, __builtin_bit_cast(h2, wtB[i]), acc[i]));
            }
        }
        __builtin_amdgcn_wave_barrier();
    }

    // ---- epilogue: 8-lane reduce, cross-wave combine, sigmoid -----------
#pragma unroll
    for (int i = 0; i < CSLOT; ++i) {
        int cell = g + 8*i;
        float v = acc[i];
        v += __shfl_xor(v, 1, 64);
        v += __shfl_xor(v, 2, 64);
        v += __shfl_xor(v, 4, 64);
        if (d4 == 0 && cell < NCELL) pRed[w][cell] = v;
    }
    __syncthreads();
    if (tid < NCELL) {
        float p = 0.f;
#pragma unroll
        for (int q = 0; q < NWAVE; ++q) p += pRed[q][tid];
        out[b*NCELL + tid] = 1.f / (1.f + expf(-(p*inv_len + bo)));
    }
}

extern "C" void kernel_launch(void* const* d_in, const int* in_sizes, int n_in,
                              void* d_out, int out_size, void* d_ws, size_t ws_size,
                              hipStream_t stream) {
    const float* ctx   = (const float*)d_in[0];
    const float* W1    = (const float*)d_in[1];
    const float* b1    = (const float*)d_in[2];
    const float* W2    = (const float*)d_in[3];
    const float* b2    = (const float*)d_in[4];
    const float* Wout  = (const float*)d_in[5];
    const float* bout  = (const float*)d_in[6];
    const int* item_idxs  = (const int*)d_in[7];
    const int* user_items = (const int*)d_in[8];
    const int* user_lens  = (const int*)d_in[9];
    float* out = (float*)d_out;
    (void)d_ws; (void)ws_size;                 // workspace no longer used

    cnn_main<<<BATCH, 512, 0, stream>>>(ctx, W1, b1, W2, b2, Wout, bout,
                                        item_idxs, user_items, user_lens, out);
}

// Round 5
// 112.873 us; speedup vs baseline: 1.2136x; 1.2136x over previous
//
#include <hip/hip_runtime.h>
#include <math.h>

// Problem constants (fixed by the reference).
#define NITEMS 50000
#define BATCH  512
#define LLEN   50
#define KTOP   20
#define HDIM   32
#define DDIM   32
#define NCH    5
#define NSEG   33             // H+1 piecewise-linear segments
#define NSCAL  200            // scalars per item
#define NCELL  100            // (c,k) cells
#define NCELLH 50             // cells per half-block
#define THRP   33             // padded LDS stride for sorted thresholds
#define NWAVE  8              // waves per block
#define CSLOTH 7              // ceil(50/8) cells per 8-lane group

typedef _Float16 h2 __attribute__((ext_vector_type(2)));

static __device__ __forceinline__ float dot2_acc(h2 a, h2 b, float c) {
#if __has_builtin(__builtin_amdgcn_fdot2)
    return __builtin_amdgcn_fdot2(a, b, c, false);
#else
    return fmaf((float)a.x, (float)b.x, fmaf((float)a.y, (float)b.y, c));
#endif
}

// ws layout (floats):
//   [0, 160)       sorted thr[c][0..31] (ascending per channel)
//   [160, 5440)    AB16 table: 5280 uints, fp16 swizzled (see below)
//   [5440, 5952)   row order (ints) from the length sort
#define WS_THRS  0
#define WS_AB16  160
#define WS_ORDER 5440

// fp16 table layout: row (c,s) = 32 uints (128 B).  Chunk d4 (0..7) = 4
// uints: [A(4d4,4d4+1), B(4d4,4d4+1), A(4d4+2,4d4+3), B(4d4+2,4d4+3)]
// where A(a,b) packs halves (lo=A_a, hi=A_b).  A lane's b128 read of its
// chunk is directly v_pk_fma_f16-ready.

// ---------------------------------------------------------------------------
// R16 post-mortem of R12-R15: the single-kernel fold is ABANDONED.  Three
// attempts (170.7 / 119.3 / 137.0 us vs 115.8 two-kernel baseline): the
// per-block prologue cannot be made both fast and register-lean inside the
// 64-VGPR envelope (R15: pk[33] regs -> 16.4 MB scratch WRITE_SIZE).
// Setup kernel below is the round-0 proven version, VERBATIM.
// ---------------------------------------------------------------------------
__global__ __launch_bounds__(256) void cnn_setup(
        const float* __restrict__ W1, const float* __restrict__ b1,
        const float* __restrict__ W2, const float* __restrict__ b2,
        const int* __restrict__ user_lens,
        float* __restrict__ ws, int* __restrict__ order) {
    const int tid = threadIdx.x;

    if (blockIdx.x < NSEG) {
        __shared__ float sW1[NCH*HDIM], sB1[NCH*HDIM], sThr[NCH*HDIM];
        __shared__ int   sRank[NCH*HDIM];
        __shared__ float sW2[NCH*HDIM*DDIM];     // 20 KB
        __shared__ float sB2[NCH*DDIM];

        for (int i = tid; i < NCH*HDIM; i += 256) { sW1[i] = W1[i]; sB1[i] = b1[i]; }
        for (int i = tid; i < NCH*HDIM*DDIM; i += 256) sW2[i] = W2[i];
        for (int i = tid; i < NCH*DDIM; i += 256) sB2[i] = b2[i];
        __syncthreads();

        for (int i = tid; i < NCH*HDIM; i += 256) {
            float w = sW1[i];
            sThr[i] = (w != 0.f) ? (-sB1[i] / w) : INFINITY;
        }
        __syncthreads();

        for (int i = tid; i < NCH*HDIM; i += 256) {
            int c = i / HDIM, h = i % HDIM;
            float thr = sThr[i];
            int rank = 0;
            for (int h2i = 0; h2i < HDIM; ++h2i) {
                float thr2 = sThr[c*HDIM + h2i];
                rank += (thr2 < thr || (thr2 == thr && h2i < h)) ? 1 : 0;
            }
            sRank[i] = rank;
            if (blockIdx.x == 0) ws[WS_THRS + c*HDIM + rank] = thr;
        }
        __syncthreads();

        const int s = blockIdx.x;                 // segment
        if (tid < NCH*DDIM) {
            int c = tid / DDIM, d = tid % DDIM;
            float A = 0.f, Bv = 0.f;
#pragma unroll
            for (int h = 0; h < HDIM; ++h) {
                float w  = sW1[c*HDIM + h];
                float bb = sB1[c*HDIM + h];
                int   r  = sRank[c*HDIM + h];
                bool active = (w > 0.f) ? (r < s) : ((w < 0.f) ? (r >= s) : (bb > 0.f));
                if (active) {
                    float w2 = sW2[(c*HDIM + h)*DDIM + d];
                    A  = fmaf(w,  w2, A);
                    Bv = fmaf(bb, w2, Bv);
                }
            }
            Bv += sB2[c*DDIM + d];
            unsigned short* ab = (unsigned short*)(ws + WS_AB16);
            int d4 = d >> 2, dd = d & 3;
            int base = ((c*NSEG + s)*32 + d4*4)*2;          // ushort index
            _Float16 ah = (_Float16)A, bh = (_Float16)Bv;
            ab[base + 4*(dd>>1) + (dd&1)]     = __builtin_bit_cast(unsigned short, ah);
            ab[base + 4*(dd>>1) + 2 + (dd&1)] = __builtin_bit_cast(unsigned short, bh);
        }
    } else {
        // ---- counting sort of rows by len (ascending) --------------------
        __shared__ int sHist[LLEN + 1];
        for (int i = tid; i <= LLEN; i += 256) sHist[i] = 0;
        __syncthreads();
        for (int i = tid; i < BATCH; i += 256) atomicAdd(&sHist[user_lens[i]], 1);
        __syncthreads();
        if (tid == 0) {
            int accum = 0;
            for (int l = 1; l <= LLEN; ++l) { int c = sHist[l]; sHist[l] = accum; accum += c; }
        }
        __syncthreads();
        for (int i = tid; i < BATCH; i += 256) {
            int pos = atomicAdd(&sHist[user_lens[i]], 1);
            order[pos] = i;
        }
    }
}

// ---------------------------------------------------------------------------
// R16 main: HALF-ROW blocks.  Counters said main is latency/occupancy-bound
// (VALUBusy 13-18%, HBM 5%, Occupancy 42%): grid 512 x 8 waves = 4096 waves
// on an 8192-wave machine.  Cell (c,k) needs only scalars c*40+k and
// c*40+20+k, so the k-dimension splits cleanly: block = (row, half), half
// h owns k in [10h, 10h+10) -> 100 scalars, 50 cells, own 50 outputs, NO
// cross-block reduction.  Grid 1024 (4 blocks/CU -> 100% occupancy
// ceiling); per-item serial work halves (phase S 4->2 rounds, phase C
// 13->7 slots); register arrays shrink 13->7 (spill-safe); LDS 29.8 KB.
// Per-cell arithmetic is op-for-op identical to the proven R11 kernel.
// DO NOT restructure the stripe loop without checking WRITE_SIZE for
// spills (R7/R10/R15 pathology).
// ---------------------------------------------------------------------------
__global__ __launch_bounds__(512, 8) void cnn_main(
        const float* __restrict__ ctx,  const float* __restrict__ ws,
        const float* __restrict__ Wout, const float* __restrict__ bout,
        const int* __restrict__ item_idxs, const int* __restrict__ user_items,
        const int* __restrict__ user_lens, const int* __restrict__ order,
        float* __restrict__ out) {
    __shared__ unsigned int sAB16[NCH*NSEG*32];  // 21120 B, swizzled fp16
    __shared__ float  sThrS[NCH*THRP];           // sorted thr, stride 33
    __shared__ uint2  sxo[NWAVE][NCELLH];        // {x0h|off0<<16, x1h|off1<<16}
    __shared__ uint2  sWt[NCELLH*8];             // [cellL*8+d4] target wt bits
    __shared__ float  pRed[NWAVE][NCELLH];       // per-wave scalar partials

    const int tid  = threadIdx.x;
    const int w    = tid >> 6;              // wave 0..7
    const int lane = tid & 63;
    const int g    = lane >> 3;             // cell sub-group 0..7
    const int d4   = lane & 7;              // covers d = 4*d4 .. 4*d4+3

    // Stage fp16 table + sorted thresholds.
    const uint4* ABg = reinterpret_cast<const uint4*>(ws + WS_AB16);
    uint4* sAB4 = reinterpret_cast<uint4*>(sAB16);
    for (int i = tid; i < NCH*NSEG*8; i += 512) sAB4[i] = ABg[i];
    for (int i = tid; i < NCH*THRP; i += 512) {
        int c = i / THRP, j = i - c*THRP;
        sThrS[i] = (j < HDIM) ? ws[WS_THRS + c*HDIM + j] : 0.f;
    }

    // Block -> (row rank, cell half).  Sorted pairing preserved on rowSlot.
    const int rowSlot = blockIdx.x >> 1;
    const int half    = blockIdx.x & 1;     // k in [10*half, 10*half+10)
    const int rank = (rowSlot < 256) ? rowSlot : (767 - rowSlot);
    const int b    = order[rank];
    const int len  = user_lens[b];          // >= 1
    const float inv_len = 1.f / (float)len;
    const float bo = bout[0];
    const h2 wv0 = {(_Float16)Wout[4*d4],     (_Float16)Wout[4*d4 + 1]};
    const h2 wv1 = {(_Float16)Wout[4*d4 + 2], (_Float16)Wout[4*d4 + 3]};

    // Per-(lane,round) phase-S constants (fixed across items).
    // Local enumeration lidx in [0,100): c = lidx/20, rr = lidx%20,
    // slot = rr/10, kk = rr%10.  Local cell = c*10+kk; row scalar index
    // = c*40 + slot*20 + half*10 + kk.
    int sc[2], sdst[2], sgi[2];
#pragma unroll
    for (int r = 0; r < 2; ++r) {
        int lidx = lane + 64*r;
        int c    = lidx / 20, rr = lidx - c*20;
        int slot = rr / 10,  kk = rr - slot*10;
        sc[r]   = (lidx < 100) ? c : 0;
        sdst[r] = (c*10 + kk)*8 + slot*4;   // byte offset in sxo[w]
        sgi[r]  = c*40 + slot*20 + half*10 + kk;
    }

    const int nstripe = (len > w) ? ((len - w + NWAVE - 1) / NWAVE) : 0;

    unsigned int wtA[CSLOTH], wtB[CSLOTH];  // target rep * Wout (h2 bits)
    float acc[CSLOTH];
#pragma unroll
    for (int i = 0; i < CSLOTH; ++i) acc[i] = 0.f;

    char* sxoB = (char*)&sxo[w][0];

    __syncthreads();                        // staging visible to all waves

    // Prefetch this wave's first stripe item (overlaps wave 0's target).
    float xp[2] = {0.f, 0.f};
    if (nstripe > 0) {
        const float* row = ctx + (size_t)user_items[b*LLEN + w] * NSCAL;
#pragma unroll
        for (int r = 0; r < 2; ++r) {
            int lidx = lane + 64*r;
            if (lidx < 100) xp[r] = row[sgi[r]];
        }
    }

    // ======== target item: wave 0 only, broadcast via sWt ================
    if (w == 0) {
        float xt[2] = {0.f, 0.f};
        const float* row = ctx + (size_t)item_idxs[b] * NSCAL;
#pragma unroll
        for (int r = 0; r < 2; ++r) {
            int lidx = lane + 64*r;
            if (lidx < 100) xt[r] = row[sgi[r]];
        }
#pragma unroll
        for (int r = 0; r < 2; ++r) {
            int lidx = lane + 64*r;
            if (lidx < 100) {
                float xv = xt[r];
                int base = sc[r]*THRP;
                int pos = 0;
                pos += (sThrS[base + pos + 15] < xv) ? 16 : 0;
                pos += (sThrS[base + pos + 7]  < xv) ? 8  : 0;
                pos += (sThrS[base + pos + 3]  < xv) ? 4  : 0;
                pos += (sThrS[base + pos + 1]  < xv) ? 2  : 0;
                pos += (sThrS[base + pos]      < xv) ? 1  : 0;
                unsigned int off = (unsigned int)((sc[r]*NSEG + pos) << 7);
                _Float16 xh = (_Float16)xv;
                unsigned int word = (unsigned int)__builtin_bit_cast(unsigned short, xh)
                                  | (off << 16);
                *(unsigned int*)(sxoB + sdst[r]) = word;
            }
        }
        __builtin_amdgcn_wave_barrier();
#pragma unroll
        for (int i = 0; i < CSLOTH; ++i) {
            int cell = g + 8*i;
            if (cell < NCELLH) {
                uint2 xo = sxo[0][cell];
                const uint4* p0 = (const uint4*)((const char*)sAB16 + (xo.x >> 16) + (d4 << 4));
                const uint4* p1 = (const uint4*)((const char*)sAB16 + (xo.y >> 16) + (d4 << 4));
                uint4 q0 = *p0, q1 = *p1;
                _Float16 x0h = __builtin_bit_cast(_Float16, (unsigned short)(xo.x & 0xffffu));
                _Float16 x1h = __builtin_bit_cast(_Float16, (unsigned short)(xo.y & 0xffffu));
                h2 x0 = {x0h, x0h}, x1 = {x1h, x1h};
                h2 repa = (x0 * __builtin_bit_cast(h2, q0.x) + __builtin_bit_cast(h2, q0.y))
                        * (x1 * __builtin_bit_cast(h2, q1.x) + __builtin_bit_cast(h2, q1.y));
                h2 repb = (x0 * __builtin_bit_cast(h2, q0.z) + __builtin_bit_cast(h2, q0.w))
                        * (x1 * __builtin_bit_cast(h2, q1.z) + __builtin_bit_cast(h2, q1.w));
                wtA[i] = __builtin_bit_cast(unsigned int, (h2)(repa * wv0));
                wtB[i] = __builtin_bit_cast(unsigned int, (h2)(repb * wv1));
                sWt[cell*8 + d4] = make_uint2(wtA[i], wtB[i]);
            }
        }
    }
    __syncthreads();                        // sWt ready for all waves

    if (w != 0) {
#pragma unroll
        for (int i = 0; i < CSLOTH; ++i) {
            int cell = g + 8*i;
            if (cell < NCELLH) {
                uint2 v = sWt[cell*8 + d4];
                wtA[i] = v.x; wtB[i] = v.y;
            }
        }
    }

    // ======== stripe items (this wave only; no per-item barriers) ========
    for (int j = 0; j < nstripe; ++j) {
        float xc[2];
#pragma unroll
        for (int r = 0; r < 2; ++r) xc[r] = xp[r];

        // prefetch next stripe item (latency hidden behind S+C)
        if (j + 1 < nstripe) {
            const float* row = ctx + (size_t)user_items[b*LLEN + w + NWAVE*(j+1)] * NSCAL;
#pragma unroll
            for (int r = 0; r < 2; ++r) {
                int lidx = lane + 64*r;
                if (lidx < 100) xp[r] = row[sgi[r]];
            }
        }

        // ---- phase S: binary-search segment, pack {fp16(x)|rowoff} ------
#pragma unroll
        for (int r = 0; r < 2; ++r) {
            int lidx = lane + 64*r;
            if (lidx < 100) {
                float xv = xc[r];
                int base = sc[r]*THRP;
                int pos = 0;
                pos += (sThrS[base + pos + 15] < xv) ? 16 : 0;
                pos += (sThrS[base + pos + 7]  < xv) ? 8  : 0;
                pos += (sThrS[base + pos + 3]  < xv) ? 4  : 0;
                pos += (sThrS[base + pos + 1]  < xv) ? 2  : 0;
                pos += (sThrS[base + pos]      < xv) ? 1  : 0;
                unsigned int off = (unsigned int)((sc[r]*NSEG + pos) << 7);
                _Float16 xh = (_Float16)xv;
                unsigned int word = (unsigned int)__builtin_bit_cast(unsigned short, xh)
                                  | (off << 16);
                *(unsigned int*)(sxoB + sdst[r]) = word;
            }
        }
        __builtin_amdgcn_wave_barrier();

        // ---- phase C: 50 cells x 32 d by this wave alone -----------------
#pragma unroll
        for (int i = 0; i < CSLOTH; ++i) {
            int cell = g + 8*i;
            if (cell < NCELLH) {
                uint2 xo = sxo[w][cell];
                const uint4* p0 = (const uint4*)((const char*)sAB16 + (xo.x >> 16) + (d4 << 4));
                const uint4* p1 = (const uint4*)((const char*)sAB16 + (xo.y >> 16) + (d4 << 4));
                uint4 q0 = *p0, q1 = *p1;
                _Float16 x0h = __builtin_bit_cast(_Float16, (unsigned short)(xo.x & 0xffffu));
                _Float16 x1h = __builtin_bit_cast(_Float16, (unsigned short)(xo.y & 0xffffu));
                h2 x0 = {x0h, x0h}, x1 = {x1h, x1h};
                h2 repa = (x0 * __builtin_bit_cast(h2, q0.x) + __builtin_bit_cast(h2, q0.y))
                        * (x1 * __builtin_bit_cast(h2, q1.x) + __builtin_bit_cast(h2, q1.y));
                h2 repb = (x0 * __builtin_bit_cast(h2, q0.z) + __builtin_bit_cast(h2, q0.w))
                        * (x1 * __builtin_bit_cast(h2, q1.z) + __builtin_bit_cast(h2, q1.w));
                acc[i] = dot2_acc(repa, __builtin_bit_cast(h2, wtA[i]),
                         dot2_acc(repb, __builtin_bit_cast(h2, wtB[i]), acc[i]));
            }
        }
        __builtin_amdgcn_wave_barrier();
    }

    // ---- epilogue: 8-lane reduce, cross-wave combine, sigmoid -----------
#pragma unroll
    for (int i = 0; i < CSLOTH; ++i) {
        int cell = g + 8*i;
        float v = acc[i];
        v += __shfl_xor(v, 1, 64);
        v += __shfl_xor(v, 2, 64);
        v += __shfl_xor(v, 4, 64);
        if (d4 == 0 && cell < NCELLH) pRed[w][cell] = v;
    }
    __syncthreads();
    if (tid < NCELLH) {
        float p = 0.f;
#pragma unroll
        for (int q = 0; q < NWAVE; ++q) p += pRed[q][tid];
        int cellG = (tid / 10)*KTOP + half*10 + (tid % 10);
        out[b*NCELL + cellG] = 1.f / (1.f + expf(-(p*inv_len + bo)));
    }
}

extern "C" void kernel_launch(void* const* d_in, const int* in_sizes, int n_in,
                              void* d_out, int out_size, void* d_ws, size_t ws_size,
                              hipStream_t stream) {
    const float* ctx   = (const float*)d_in[0];
    const float* W1    = (const float*)d_in[1];
    const float* b1    = (const float*)d_in[2];
    const float* W2    = (const float*)d_in[3];
    const float* b2    = (const float*)d_in[4];
    const float* Wout  = (const float*)d_in[5];
    const float* bout  = (const float*)d_in[6];
    const int* item_idxs  = (const int*)d_in[7];
    const int* user_items = (const int*)d_in[8];
    const int* user_lens  = (const int*)d_in[9];
    float* out = (float*)d_out;
    float* ws  = (float*)d_ws;                 // uses 23,808 B
    int*   order = (int*)(ws + WS_ORDER);

    cnn_setup<<<NSEG + 1, 256, 0, stream>>>(W1, b1, W2, b2, user_lens, ws, order);
    cnn_main<<<2*BATCH, 512, 0, stream>>>(ctx, ws, Wout, bout,
                                          item_idxs, user_items, user_lens,
                                          order, out);
}